// Round 2
// baseline (403.826 us; speedup 1.0000x reference)
//
#include <hip/hip_runtime.h>

#define EPS 1e-8f
#define BM 128
#define BN 128
#define BK 32

typedef __attribute__((ext_vector_type(8))) short bf16x8;   // 8 bf16 = 4 VGPRs
typedef __attribute__((ext_vector_type(4))) float f32x4;    // MFMA C/D

// RNE float -> bf16 (inputs are finite normals; no NaN handling needed)
__device__ inline unsigned short f2bf(float f) {
    union { float f; unsigned u; } c; c.f = f;
    unsigned u = c.u;
    return (unsigned short)((u + 0x7fffu + ((u >> 16) & 1u)) >> 16);
}

// One wave per row over BOTH matrices: norms + bf16 conversion, single launch.
// Rows [0,M): x2 -> Abf/nA.  Rows [M,M+N): x1 -> Bbf/nB.
__global__ void prep_kernel(const float* __restrict__ x2, const float* __restrict__ x1,
                            unsigned short* __restrict__ Abf, unsigned short* __restrict__ Bbf,
                            float* __restrict__ nA, float* __restrict__ nB,
                            int M, int N, int K) {
    const int r = blockIdx.x * 4 + (threadIdx.x >> 6);
    const int lane = threadIdx.x & 63;
    if (r >= M + N) return;
    const float* p;
    unsigned short* q;
    float* nrm;
    if (r < M) { p = x2 + (size_t)r * K;      q = Abf + (size_t)r * K;      nrm = nA + r; }
    else       { p = x1 + (size_t)(r - M) * K; q = Bbf + (size_t)(r - M) * K; nrm = nB + (r - M); }
    float ss = 0.f;
    for (int base = lane * 4; base < K; base += 256) {
        float4 v = *(const float4*)(p + base);
        ss += v.x * v.x + v.y * v.y + v.z * v.z + v.w * v.w;
        ushort4 o;
        o.x = f2bf(v.x); o.y = f2bf(v.y); o.z = f2bf(v.z); o.w = f2bf(v.w);
        *(ushort4*)(q + base) = o;
    }
#pragma unroll
    for (int off = 32; off > 0; off >>= 1) ss += __shfl_down(ss, off, 64);
    if (lane == 0) *nrm = sqrtf(ss);
}

#define GLOAD_LDS16(g, l)                                                         \
    __builtin_amdgcn_global_load_lds(                                             \
        (const __attribute__((address_space(1))) unsigned int*)(g),               \
        (__attribute__((address_space(3))) unsigned int*)(l), 16, 0, 0)

// C[m,n] = A[m,:]·B[n,:] / max(nA[m]*nB[n], eps). A=[M][K] bf16, B=[N][K] bf16.
//
// LDS holds FRAGMENT-ORDER subtiles: for subtile s (16 rows of a tile, one BK
// slab), element [s*512 + lane*8 .. +8] = X[tile0 + s*16 + (lane&15)]
//                                          [kk + (lane>>4)*8 .. +8]
// which is exactly the mfma_16x16x32 A/B fragment for that lane. Staged via
// global_load_lds (LDS dst = uniform base + lane*16), so every fragment
// ds_read_b128 is lane-contiguous -> zero bank conflicts, single vaddr.
__global__ __launch_bounds__(256) void gemm_cos_kernel(
    const unsigned short* __restrict__ A, const unsigned short* __restrict__ B,
    const float* __restrict__ nA, const float* __restrict__ nB,
    float* __restrict__ C, int M, int N, int K) {
    __shared__ unsigned short As[8 * 512];   // 8 subtiles x 64 lanes x 8 bf16 = 8 KB
    __shared__ unsigned short Bs[8 * 512];

    const int tid = threadIdx.x;
    const int wave = tid >> 6;
    const int lane = tid & 63;
    const int wm = wave >> 1;      // 2x2 wave grid over the 128x128 tile
    const int wn = wave & 1;
    const int quad = lane >> 4;
    const int l16 = lane & 15;

    const int row0 = blockIdx.y * BM;
    const int col0 = blockIdx.x * BN;

    // Staging: wave stages A-subtiles {2w, 2w+1} and B-subtiles {2w, 2w+1}.
    // Lane's global source = its own fragment slot.
    const int fr = l16;            // fragment row within subtile
    const int fk = quad * 8;       // fragment k-chunk

    const unsigned short* gA0 = A + (size_t)(row0 + (2 * wave) * 16 + fr) * K + fk;
    const unsigned short* gA1 = gA0 + 16 * (size_t)K;
    const unsigned short* gB0 = B + (size_t)(col0 + (2 * wave) * 16 + fr) * K + fk;
    const unsigned short* gB1 = gB0 + 16 * (size_t)K;
    unsigned short* lA0 = As + (2 * wave) * 512;       // wave-uniform LDS bases
    unsigned short* lA1 = As + (2 * wave + 1) * 512;
    unsigned short* lB0 = Bs + (2 * wave) * 512;
    unsigned short* lB1 = Bs + (2 * wave + 1) * 512;

    f32x4 acc[4][4] = {};

    for (int kk = 0; kk < K; kk += BK) {
        GLOAD_LDS16(gA0, lA0);
        GLOAD_LDS16(gA1, lA1);
        GLOAD_LDS16(gB0, lB0);
        GLOAD_LDS16(gB1, lB1);
        gA0 += BK; gA1 += BK; gB0 += BK; gB1 += BK;
        __syncthreads();   // drains vmcnt: LDS tiles complete

        bf16x8 af[4], bfr[4];
#pragma unroll
        for (int mi = 0; mi < 4; mi++)
            af[mi] = *(const bf16x8*)(As + (wm * 4 + mi) * 512 + lane * 8);
#pragma unroll
        for (int ni = 0; ni < 4; ni++)
            bfr[ni] = *(const bf16x8*)(Bs + (wn * 4 + ni) * 512 + lane * 8);
#pragma unroll
        for (int mi = 0; mi < 4; mi++)
#pragma unroll
            for (int ni = 0; ni < 4; ni++)
                acc[mi][ni] = __builtin_amdgcn_mfma_f32_16x16x32_bf16(
                    af[mi], bfr[ni], acc[mi][ni], 0, 0, 0);
        __syncthreads();   // all waves done reading before next stage overwrites
    }

    // Epilogue: D[row=quad*4+r][col=l16] per 16x16 tile (m89/m91-verified layout)
    const int crow_base = row0 + wm * 64 + quad * 4;
    const int ccol_base = col0 + wn * 64 + l16;

    float rb[4];
#pragma unroll
    for (int ni = 0; ni < 4; ni++) rb[ni] = nB[ccol_base + ni * 16];

#pragma unroll
    for (int mi = 0; mi < 4; mi++) {
#pragma unroll
        for (int r = 0; r < 4; r++) {
            const int row = crow_base + mi * 16 + r;
            const float ra = nA[row];
            float* outp = C + (size_t)row * N + ccol_base;
#pragma unroll
            for (int ni = 0; ni < 4; ni++) {
                outp[ni * 16] = acc[mi][ni][r] / fmaxf(ra * rb[ni], EPS);
            }
        }
    }
}

// Correctness-guard fallback (weird shapes / tiny ws): naive fp32.
__global__ void naive_kernel(const float* __restrict__ x1, const float* __restrict__ x2,
                             float* __restrict__ out, int N, int M, int K) {
    long long idx = (long long)blockIdx.x * blockDim.x + threadIdx.x;
    if (idx >= (long long)M * N) return;
    int m = (int)(idx / N), n = (int)(idx % N);
    const float* a = x2 + (size_t)m * K;
    const float* b = x1 + (size_t)n * K;
    float dot = 0.f, sa = 0.f, sb = 0.f;
    for (int k = 0; k < K; k++) {
        float av = a[k], bv = b[k];
        dot += av * bv; sa += av * av; sb += bv * bv;
    }
    out[idx] = dot / fmaxf(sqrtf(sa) * sqrtf(sb), EPS);
}

extern "C" void kernel_launch(void* const* d_in, const int* in_sizes, int n_in,
                              void* d_out, int out_size, void* d_ws, size_t ws_size,
                              hipStream_t stream) {
    const float* x1 = (const float*)d_in[0];   // [N][K]
    const float* x2 = (const float*)d_in[1];   // [M][K]
    float* out = (float*)d_out;                // [M][N]
    const int K = 512;
    const int N = in_sizes[0] / K;
    const int M = in_sizes[1] / K;

    const size_t szA = (size_t)M * K * sizeof(unsigned short);
    const size_t szB = (size_t)N * K * sizeof(unsigned short);
    const size_t need = szA + szB + (size_t)(M + N) * sizeof(float);

    const bool fast = (in_sizes[0] % K == 0) && (in_sizes[1] % K == 0) &&
                      (M % BM == 0) && (N % BN == 0) && (K % BK == 0) &&
                      (need <= ws_size) && ((long long)M * N == (long long)out_size);

    if (fast) {
        unsigned short* Abf = (unsigned short*)d_ws;                       // x2 bf16
        unsigned short* Bbf = (unsigned short*)((char*)d_ws + szA);        // x1 bf16
        float* nA = (float*)((char*)d_ws + szA + szB);                     // ||x2[m]||
        float* nB = nA + M;                                                // ||x1[n]||
        prep_kernel<<<(M + N + 3) / 4, 256, 0, stream>>>(x2, x1, Abf, Bbf, nA, nB, M, N, K);
        dim3 grid(N / BN, M / BM);
        gemm_cos_kernel<<<grid, 256, 0, stream>>>(Abf, Bbf, nA, nB, out, M, N, K);
    } else {
        long long total = (long long)M * N;
        int blocks = (int)((total + 255) / 256);
        naive_kernel<<<blocks, 256, 0, stream>>>(x1, x2, out, N, M, K);
    }
}

// Round 3
// 383.938 us; speedup vs baseline: 1.0518x; 1.0518x over previous
//
#include <hip/hip_runtime.h>

#define EPS 1e-8f
#define BM 128
#define BN 128
#define BK 32
#define KITERS_MAX 16   // K=512 / BK

typedef __attribute__((ext_vector_type(8))) short bf16x8;   // 8 bf16 = 4 VGPRs
typedef __attribute__((ext_vector_type(4))) float f32x4;    // MFMA C/D

// RNE float -> bf16 (inputs are finite normals; no NaN handling needed)
__device__ inline unsigned short f2bf(float f) {
    union { float f; unsigned u; } c; c.f = f;
    unsigned u = c.u;
    return (unsigned short)((u + 0x7fffu + ((u >> 16) & 1u)) >> 16);
}

// One wave per row over BOTH matrices: norms + bf16 conversion, single launch.
// Rows [0,M): x2 -> Abf/nA.  Rows [M,M+N): x1 -> Bbf/nB.
__global__ void prep_kernel(const float* __restrict__ x2, const float* __restrict__ x1,
                            unsigned short* __restrict__ Abf, unsigned short* __restrict__ Bbf,
                            float* __restrict__ nA, float* __restrict__ nB,
                            int M, int N, int K) {
    const int r = blockIdx.x * 4 + (threadIdx.x >> 6);
    const int lane = threadIdx.x & 63;
    if (r >= M + N) return;
    const float* p;
    unsigned short* q;
    float* nrm;
    if (r < M) { p = x2 + (size_t)r * K;      q = Abf + (size_t)r * K;      nrm = nA + r; }
    else       { p = x1 + (size_t)(r - M) * K; q = Bbf + (size_t)(r - M) * K; nrm = nB + (r - M); }
    float ss = 0.f;
    for (int base = lane * 4; base < K; base += 256) {
        float4 v = *(const float4*)(p + base);
        ss += v.x * v.x + v.y * v.y + v.z * v.z + v.w * v.w;
        ushort4 o;
        o.x = f2bf(v.x); o.y = f2bf(v.y); o.z = f2bf(v.z); o.w = f2bf(v.w);
        *(ushort4*)(q + base) = o;
    }
#pragma unroll
    for (int off = 32; off > 0; off >>= 1) ss += __shfl_down(ss, off, 64);
    if (lane == 0) *nrm = sqrtf(ss);
}

#define GLOAD_LDS16(g, l)                                                         \
    __builtin_amdgcn_global_load_lds(                                             \
        (const __attribute__((address_space(1))) unsigned int*)(g),               \
        (__attribute__((address_space(3))) unsigned int*)(l), 16, 0, 0)

// C[m,n] = A[m,:]·B[n,:] / max(nA[m]*nB[n], eps). A=[M][K] bf16, B=[N][K] bf16.
//
// LDS holds FRAGMENT-ORDER subtiles (conflict-free ds_read_b128, single vaddr):
// subtile s, element [s*512 + lane*8 .. +8] = X[tile0+s*16+(lane&15)][kk+(lane>>4)*8 ..+8]
// = exactly lane's mfma_16x16x32 fragment. Staged via global_load_lds (dst =
// uniform base + lane*16).
//
// K-loop: DOUBLE-BUFFERED, ONE barrier/iter. Prefetch of tile k+1 into the
// alternate buffer is issued before computing tile k; the compiler's
// vmcnt(0)-at-barrier then drains a prefetch that has had a full compute
// phase to complete -> drain hidden. Writing buf[nxt] during compute of
// buf[cur] is safe: all reads of buf[nxt] finished before the PREVIOUS
// barrier (block-wide), so no wave can still be reading it.
__global__ __launch_bounds__(256, 4) void gemm_cos_kernel(
    const unsigned short* __restrict__ A, const unsigned short* __restrict__ B,
    const float* __restrict__ nA, const float* __restrict__ nB,
    float* __restrict__ C, int M, int N, int K) {
    __shared__ unsigned short As[2][8 * 512];   // 2 x 8 KB
    __shared__ unsigned short Bs[2][8 * 512];

    const int tid = threadIdx.x;
    const int wave = tid >> 6;
    const int lane = tid & 63;
    const int wm = wave >> 1;      // 2x2 wave grid over the 128x128 tile
    const int wn = wave & 1;
    const int quad = lane >> 4;
    const int l16 = lane & 15;

    const int row0 = blockIdx.y * BM;
    const int col0 = blockIdx.x * BN;

    // Staging: wave stages A-subtiles {2w,2w+1} and B-subtiles {2w,2w+1}.
    // Lane's global source = its own fragment slot.
    const int fr = l16;            // fragment row within subtile
    const int fk = quad * 8;       // fragment k-chunk

    const unsigned short* gA0 = A + (size_t)(row0 + (2 * wave) * 16 + fr) * K + fk;
    const unsigned short* gA1 = gA0 + 16 * (size_t)K;
    const unsigned short* gB0 = B + (size_t)(col0 + (2 * wave) * 16 + fr) * K + fk;
    const unsigned short* gB1 = gB0 + 16 * (size_t)K;
    const int ldsOff = (2 * wave) * 512;   // wave-uniform LDS subtile base

    f32x4 acc[4][4] = {};

    const int niter = K / BK;

    // Prologue: stage k=0 into buffer 0.
    GLOAD_LDS16(gA0, &As[0][ldsOff]);
    GLOAD_LDS16(gA1, &As[0][ldsOff + 512]);
    GLOAD_LDS16(gB0, &Bs[0][ldsOff]);
    GLOAD_LDS16(gB1, &Bs[0][ldsOff + 512]);
    gA0 += BK; gA1 += BK; gB0 += BK; gB1 += BK;
    __syncthreads();   // buf0 ready (vmcnt(0) drained at barrier)

    for (int k = 0; k < niter; k++) {
        const int cur = k & 1;
        const int nxt = cur ^ 1;
        if (k + 1 < niter) {       // async prefetch of tile k+1 (hidden by compute)
            GLOAD_LDS16(gA0, &As[nxt][ldsOff]);
            GLOAD_LDS16(gA1, &As[nxt][ldsOff + 512]);
            GLOAD_LDS16(gB0, &Bs[nxt][ldsOff]);
            GLOAD_LDS16(gB1, &Bs[nxt][ldsOff + 512]);
            gA0 += BK; gA1 += BK; gB0 += BK; gB1 += BK;
        }

        bf16x8 af[4], bfr[4];
#pragma unroll
        for (int mi = 0; mi < 4; mi++)
            af[mi] = *(const bf16x8*)(&As[cur][(wm * 4 + mi) * 512 + lane * 8]);
#pragma unroll
        for (int ni = 0; ni < 4; ni++)
            bfr[ni] = *(const bf16x8*)(&Bs[cur][(wn * 4 + ni) * 512 + lane * 8]);
#pragma unroll
        for (int mi = 0; mi < 4; mi++)
#pragma unroll
            for (int ni = 0; ni < 4; ni++)
                acc[mi][ni] = __builtin_amdgcn_mfma_f32_16x16x32_bf16(
                    af[mi], bfr[ni], acc[mi][ni], 0, 0, 0);

        __syncthreads();   // single barrier: reads of buf[cur] done + prefetch drained
    }

    // Epilogue: D[row=quad*4+r][col=l16] per 16x16 tile (m89/m91-verified layout)
    const int crow_base = row0 + wm * 64 + quad * 4;
    const int ccol_base = col0 + wn * 64 + l16;

    float rb[4];
#pragma unroll
    for (int ni = 0; ni < 4; ni++) rb[ni] = nB[ccol_base + ni * 16];

#pragma unroll
    for (int mi = 0; mi < 4; mi++) {
#pragma unroll
        for (int r = 0; r < 4; r++) {
            const int row = crow_base + mi * 16 + r;
            const float ra = nA[row];
            float* outp = C + (size_t)row * N + ccol_base;
#pragma unroll
            for (int ni = 0; ni < 4; ni++) {
                outp[ni * 16] = acc[mi][ni][r] / fmaxf(ra * rb[ni], EPS);
            }
        }
    }
}

// Correctness-guard fallback (weird shapes / tiny ws): naive fp32.
__global__ void naive_kernel(const float* __restrict__ x1, const float* __restrict__ x2,
                             float* __restrict__ out, int N, int M, int K) {
    long long idx = (long long)blockIdx.x * blockDim.x + threadIdx.x;
    if (idx >= (long long)M * N) return;
    int m = (int)(idx / N), n = (int)(idx % N);
    const float* a = x2 + (size_t)m * K;
    const float* b = x1 + (size_t)n * K;
    float dot = 0.f, sa = 0.f, sb = 0.f;
    for (int k = 0; k < K; k++) {
        float av = a[k], bv = b[k];
        dot += av * bv; sa += av * av; sb += bv * bv;
    }
    out[idx] = dot / fmaxf(sqrtf(sa) * sqrtf(sb), EPS);
}

extern "C" void kernel_launch(void* const* d_in, const int* in_sizes, int n_in,
                              void* d_out, int out_size, void* d_ws, size_t ws_size,
                              hipStream_t stream) {
    const float* x1 = (const float*)d_in[0];   // [N][K]
    const float* x2 = (const float*)d_in[1];   // [M][K]
    float* out = (float*)d_out;                // [M][N]
    const int K = 512;
    const int N = in_sizes[0] / K;
    const int M = in_sizes[1] / K;

    const size_t szA = (size_t)M * K * sizeof(unsigned short);
    const size_t szB = (size_t)N * K * sizeof(unsigned short);
    const size_t need = szA + szB + (size_t)(M + N) * sizeof(float);

    const bool fast = (in_sizes[0] % K == 0) && (in_sizes[1] % K == 0) &&
                      (M % BM == 0) && (N % BN == 0) && (K % BK == 0) &&
                      (K / BK <= KITERS_MAX) &&
                      (need <= ws_size) && ((long long)M * N == (long long)out_size);

    if (fast) {
        unsigned short* Abf = (unsigned short*)d_ws;                       // x2 bf16
        unsigned short* Bbf = (unsigned short*)((char*)d_ws + szA);        // x1 bf16
        float* nA = (float*)((char*)d_ws + szA + szB);                     // ||x2[m]||
        float* nB = nA + M;                                                // ||x1[n]||
        prep_kernel<<<(M + N + 3) / 4, 256, 0, stream>>>(x2, x1, Abf, Bbf, nA, nB, M, N, K);
        dim3 grid(N / BN, M / BM);
        gemm_cos_kernel<<<grid, 256, 0, stream>>>(Abf, Bbf, nA, nB, out, M, N, K);
    } else {
        long long total = (long long)M * N;
        int blocks = (int)((total + 255) / 256);
        naive_kernel<<<blocks, 256, 0, stream>>>(x1, x2, out, N, M, K);
    }
}